// Round 7
// baseline (190.869 us; speedup 1.0000x reference)
//
#include <hip/hip_runtime.h>
#include <hip/hip_bf16.h>

#define N_EXPERTS 8
#define T_TOKENS 32768
#define D 512              // D_IN == D_OUT
#define TILE 128           // m-tile and n-tile
#define BK 64
#define NKK (D / BK)       // 8 k-steps
#define CHUNK 8192         // u16 per packed chunk (128 rows x 64 k = 16 KB)
#define TILE_U16 (NKK * CHUNK)   // 65536 u16 = 128 KB per packed m-tile
#define MT_MAX 264         // max global m-tiles (sum ceil(cnt_e/128) <= 263)
#define GRID_WG (MT_MAX * 4)     // 1056
#define SCATTER_BLOCKS (T_TOKENS / 256)   // 128
#define CONVW_BLOCKS 128                  // (e, bn, quarter)
#define LT_MAX 256
#define GEMM_GRID (N_EXPERTS * LT_MAX * 4)   // fallback grid

typedef __bf16 bf16x8 __attribute__((ext_vector_type(8)));
typedef float  f32x4  __attribute__((ext_vector_type(4)));
typedef unsigned short u16x8 __attribute__((ext_vector_type(8)));

__device__ __forceinline__ unsigned short f2bf(float f) {
    unsigned int u = __float_as_uint(f);
    u += 0x7FFFu + ((u >> 16) & 1u);   // round-to-nearest-even
    return (unsigned short)(u >> 16);
}

__device__ __forceinline__ u16x8 cvt8(float4 a, float4 b) {
    u16x8 o;
    o[0] = f2bf(a.x); o[1] = f2bf(a.y); o[2] = f2bf(a.z); o[3] = f2bf(a.w);
    o[4] = f2bf(b.x); o[5] = f2bf(b.y); o[6] = f2bf(b.z); o[7] = f2bf(b.w);
    return o;
}

__device__ __forceinline__ void gl2lds16(const void* g, void* l) {
    // async global->LDS, 16B/lane; LDS dest = wave-uniform base + lane*16
    __builtin_amdgcn_global_load_lds(
        (const __attribute__((address_space(1))) void*)g,
        (__attribute__((address_space(3))) void*)l, 16, 0, 0);
}

// ---- kernel 2: scatter token ids (fixed per-expert regions) + pack W ----
// Packed layout (both operands): per chunk, row-major [128 rows][8 slots of
// 16B]; slot s of row r holds global 16B k-block (s ^ (r&7)) -- the GEMM's
// fragment ds_read XOR hits all 32 banks, and staging is a LINEAR copy.
__global__ __launch_bounds__(256) void scatter_convw(
        const int* __restrict__ p, int* __restrict__ fill, int* __restrict__ sorted,
        const float* __restrict__ W, unsigned short* __restrict__ Wt) {
    int bid = blockIdx.x;
    int tid = threadIdx.x;
    if (bid < SCATTER_BLOCKS) {
        __shared__ int lcount[N_EXPERTS];
        __shared__ int lbase[N_EXPERTS];
        if (tid < N_EXPERTS) lcount[tid] = 0;
        __syncthreads();
        int t = bid * 256 + tid;            // always < T_TOKENS
        int e = p[t];
        int lrank = atomicAdd(&lcount[e], 1);
        __syncthreads();
        if (tid < N_EXPERTS)
            lbase[tid] = (lcount[tid] > 0) ? atomicAdd(&fill[tid], lcount[tid]) : 0;
        __syncthreads();
        // fill starts at -1 (0xFF memset), atomicAdd returns old => first rank 0
        sorted[e * T_TOKENS + (lbase[e] + 1 + lrank)] = t;
    } else {
        // pack W: one wave per row; lane l -> kk = l>>3, block b = l&7
        int i2 = bid - SCATTER_BLOCKS;           // 0..127
        int e = i2 >> 4, bn = (i2 >> 2) & 3, q = i2 & 3;
        int wave = tid >> 6, lane = tid & 63;
        int kk = lane >> 3, b = lane & 7;
        unsigned short* base = Wt + (size_t)(e * 4 + bn) * TILE_U16 + kk * CHUNK;
#pragma unroll
        for (int rr = 0; rr < 8; rr++) {
            int row = q * 32 + wave * 8 + rr;
            const float* src = W + ((size_t)e * D + bn * TILE + row) * D + lane * 8;
            float4 a = *(const float4*)src;
            float4 c = *(const float4*)(src + 4);
            *(u16x8*)&base[row * 64 + ((b ^ (row & 7)) << 3)] = cvt8(a, c);
        }
    }
}

// ---- kernel 3: gather x rows by token id into packed m-tiles ----
// one wave per row: 64 lanes x 8 fp32 = 2KB contiguous read; lane l emits
// one 16B bf16 block into chunk (l>>3) at swizzled slot. Pad rows -> zeros.
__global__ __launch_bounds__(256) void gather_pack_x(
        const float* __restrict__ x, const int* __restrict__ fill,
        const int* __restrict__ sorted, unsigned short* __restrict__ xs) {
    int m = blockIdx.x;
    int e = 0, lt = 0, tacc = 0, found = 0, cnt_e = 0;
#pragma unroll
    for (int i = 0; i < N_EXPERTS; i++) {
        int c = fill[i] + 1;                 // +1 trick (fill started at -1)
        int tiles = (c + TILE - 1) >> 7;
        if (!found && m < tacc + tiles) { e = i; lt = m - tacc; cnt_e = c; found = 1; }
        tacc += tiles;
    }
    if (!found) return;

    int tid = threadIdx.x, wave = tid >> 6, lane = tid & 63;
    int kk = lane >> 3, b = lane & 7;
    unsigned short* base = xs + (size_t)m * TILE_U16 + kk * CHUNK;
    int row0 = lt * TILE;
#pragma unroll 4
    for (int rr = 0; rr < 32; rr++) {
        int row = wave * 32 + rr;
        int r = row0 + row;
        int tok = (r < cnt_e) ? sorted[e * T_TOKENS + r] : -1;
        u16x8 v = (u16x8)0;
        if (tok >= 0) {
            const float* src = x + (size_t)tok * D + lane * 8;
            float4 a = *(const float4*)src;
            float4 c = *(const float4*)(src + 4);
            v = cvt8(a, c);
        }
        *(u16x8*)&base[row * 64 + ((b ^ (row & 7)) << 3)] = v;
    }
}

// ---- kernel 4: grouped GEMM on pre-packed operands ----
// r3's proven schedule (all-DMA dbuf, counted vmcnt(8), setprio, coalesced
// epilogue) with staging reduced to LINEAR chunk copies: every gl2lds16
// reads 1KB CONTIGUOUS (src offset == dst offset) -- m97-class DMA pattern.
// Grid 1056 = 264 global m-tiles x 4 bn; bn-siblings share bid%8 -> same XCD
// -> A-chunk fetched once per XCD, L2 serves the other 3.
__global__ __launch_bounds__(256, 2) void moe_gemm_pk(
        const unsigned short* __restrict__ xs, const unsigned short* __restrict__ Wt,
        const float* __restrict__ bias, const int* __restrict__ fill,
        const int* __restrict__ sorted, float* __restrict__ out) {
    __shared__ int s_idx[TILE];
    __shared__ unsigned short sA[2][TILE * BK];   // 32 KB
    __shared__ unsigned short sB[2][TILE * BK];   // 32 KB

    int bid = blockIdx.x;
    int w6 = bid >> 3;
    int m = (bid & 7) + (w6 >> 2) * 8;      // global m-tile 0..263
    int bn = w6 & 3;

    int e = 0, lt = 0, tacc = 0, found = 0, cnt_e = 0;
#pragma unroll
    for (int i = 0; i < N_EXPERTS; i++) {
        int c = fill[i] + 1;
        int tiles = (c + TILE - 1) >> 7;
        if (!found && m < tacc + tiles) { e = i; lt = m - tacc; cnt_e = c; found = 1; }
        tacc += tiles;
    }
    if (!found) return;
    int row0 = lt * TILE;

    int tid = threadIdx.x;
    if (tid < TILE) {
        int r = row0 + tid;
        s_idx[tid] = (r < cnt_e) ? sorted[e * T_TOKENS + r] : -1;
    }
    __syncthreads();   // also drains vmcnt -> DMA counting below starts clean

    int wave = tid >> 6, lane = tid & 63;
    int wm = (wave >> 1) * 64, wn = (wave & 1) * 64;
    int lrow = lane & 15, lq = lane >> 4;

    const unsigned short* gAc = xs + (size_t)m * TILE_U16;
    const unsigned short* gBc = Wt + (size_t)(e * 4 + bn) * TILE_U16;

#define STAGE(K, KB) do {                                                      \
    _Pragma("unroll") for (int t = 0; t < 4; t++)                              \
        gl2lds16(gAc + (size_t)(K) * CHUNK + (wave * 4 + t) * 512 + lane * 8,  \
                 &sA[KB][(wave * 4 + t) * 512]);                               \
    _Pragma("unroll") for (int t = 0; t < 4; t++)                              \
        gl2lds16(gBc + (size_t)(K) * CHUNK + (wave * 4 + t) * 512 + lane * 8,  \
                 &sB[KB][(wave * 4 + t) * 512]);                               \
} while (0)

    f32x4 acc[4][4];
#pragma unroll
    for (int i = 0; i < 4; i++)
#pragma unroll
        for (int j2 = 0; j2 < 4; j2++)
            acc[i][j2] = (f32x4){0.f, 0.f, 0.f, 0.f};

    STAGE(0, 0);   // prologue: stage(0) in flight (8 DMAs/thread)

#pragma unroll
    for (int step = 0; step < NKK; step++) {
        // top barrier: prev step's ds_reads retired -> other buffer is free
        asm volatile("s_waitcnt lgkmcnt(0)" ::: "memory");
        __builtin_amdgcn_s_barrier();
        __builtin_amdgcn_sched_barrier(0);
        if (step < NKK - 1) {
            STAGE(step + 1, (step + 1) & 1);   // issue next stage (8 DMAs)...
            __builtin_amdgcn_sched_barrier(0);
            // ...then wait ONLY for stage(step): 8 younger ops stay in flight
            asm volatile("s_waitcnt vmcnt(8)" ::: "memory");
        } else {
            asm volatile("s_waitcnt vmcnt(0)" ::: "memory");
        }
        __builtin_amdgcn_s_barrier();          // all waves' stage(step) visible
        __builtin_amdgcn_sched_barrier(0);
        const unsigned short* cA = sA[step & 1];
        const unsigned short* cB = sB[step & 1];
        __builtin_amdgcn_s_setprio(1);
#pragma unroll
        for (int ks = 0; ks < 2; ks++) {
            int cb = (ks * 4 + lq) ^ (lrow & 7);
            bf16x8 af[4], bfr[4];
#pragma unroll
            for (int i = 0; i < 4; i++)
                af[i] = *(const bf16x8*)&cA[(wm + 16 * i + lrow) * BK + cb * 8];
#pragma unroll
            for (int j2 = 0; j2 < 4; j2++)
                bfr[j2] = *(const bf16x8*)&cB[(wn + 16 * j2 + lrow) * BK + cb * 8];
#pragma unroll
            for (int i = 0; i < 4; i++)
#pragma unroll
                for (int j2 = 0; j2 < 4; j2++)
                    acc[i][j2] = __builtin_amdgcn_mfma_f32_16x16x32_bf16(
                        af[i], bfr[j2], acc[i][j2], 0, 0, 0);
        }
        __builtin_amdgcn_s_setprio(0);
    }
#undef STAGE

    // ---- coalesced epilogue: fold bias, stage C through LDS (reuse sA as
    // 64x128 f32 = 32 KB), write full 512B row-segments
#pragma unroll
    for (int j2 = 0; j2 < 4; j2++) {
        float bv = bias[e * D + bn * TILE + wn + 16 * j2 + lrow];
#pragma unroll
        for (int i = 0; i < 4; i++)
#pragma unroll
            for (int r = 0; r < 4; r++)
                acc[i][j2][r] += bv;
    }

    float* ct = (float*)&sA[0][0];   // 32 KB: 64 rows x 128 cols f32
#pragma unroll
    for (int p = 0; p < 2; p++) {
        // MFMA ds_reads done (p=0) / pass-0 ct reads done (p=1)
        asm volatile("s_waitcnt lgkmcnt(0)" ::: "memory");
        __builtin_amdgcn_s_barrier();
        if ((wave >> 1) == p) {      // the 2 waves owning rows [64p, 64p+64)
#pragma unroll
            for (int i = 0; i < 4; i++)
#pragma unroll
                for (int j2 = 0; j2 < 4; j2++)
#pragma unroll
                    for (int r = 0; r < 4; r++)
                        ct[(16 * i + lq * 4 + r) * TILE + wn + 16 * j2 + lrow]
                            = acc[i][j2][r];
        }
        asm volatile("s_waitcnt lgkmcnt(0)" ::: "memory");
        __builtin_amdgcn_s_barrier();
#pragma unroll
        for (int k = 0; k < 8; k++) {
            int u = tid + 256 * k;
            int row = u >> 5, ch = u & 31;
            int tok = s_idx[p * 64 + row];
            f32x4 v = *(const f32x4*)&ct[row * TILE + ch * 4];
            if (tok >= 0)
                *(f32x4*)&out[(size_t)tok * D + bn * TILE + ch * 4] = v;
        }
    }
}

// ---- fallback (tiny ws): fp32-load GEMM, fixed-region decode ----
__global__ __launch_bounds__(256) void moe_gemm_f32(
        const float* __restrict__ x, const float* __restrict__ W,
        const float* __restrict__ bias, const int* __restrict__ fill,
        const int* __restrict__ sorted, float* __restrict__ out) {
    __shared__ int s_idx[TILE];
    __shared__ unsigned short sA[TILE][BK + 8];
    __shared__ unsigned short sB[TILE][BK + 8];

    int bid = blockIdx.x;
    int e = bid & 7;
    int cnt = fill[e] + 1;
    int j = bid >> 3;
    int lt = j >> 2, bn = j & 3;
    int row0 = lt * TILE;
    if (row0 >= cnt) return;

    int tid = threadIdx.x;
    if (tid < TILE) {
        int r = row0 + tid;
        s_idx[tid] = (r < cnt) ? sorted[e * T_TOKENS + r] : -1;
    }
    __syncthreads();

    const float* Wbp = W + (size_t)e * D * D + (size_t)(bn * TILE) * D;

    f32x4 acc[4][4];
#pragma unroll
    for (int i = 0; i < 4; i++)
#pragma unroll
        for (int j2 = 0; j2 < 4; j2++)
            acc[i][j2] = (f32x4){0.f, 0.f, 0.f, 0.f};

    int wave = tid >> 6, lane = tid & 63;
    int wm = (wave >> 1) * 64, wn = (wave & 1) * 64;
    int lrow = lane & 15, lq = lane >> 4;

    for (int kk = 0; kk < D; kk += BK) {
#pragma unroll
        for (int i = 0; i < 8; i++) {
            int flat = tid + i * 256;
            int r = flat >> 4, c = (flat & 15) << 2;
            int tok = s_idx[r];
            float4 v = make_float4(0.f, 0.f, 0.f, 0.f);
            if (tok >= 0) v = *(const float4*)(x + (size_t)tok * D + kk + c);
            ushort4 w4;
            w4.x = f2bf(v.x); w4.y = f2bf(v.y); w4.z = f2bf(v.z); w4.w = f2bf(v.w);
            *(ushort4*)&sA[r][c] = w4;
        }
#pragma unroll
        for (int i = 0; i < 8; i++) {
            int flat = tid + i * 256;
            int r = flat >> 4, c = (flat & 15) << 2;
            float4 v = *(const float4*)(Wbp + (size_t)r * D + kk + c);
            ushort4 w4;
            w4.x = f2bf(v.x); w4.y = f2bf(v.y); w4.z = f2bf(v.z); w4.w = f2bf(v.w);
            *(ushort4*)&sB[r][c] = w4;
        }
        __syncthreads();
#pragma unroll
        for (int ks = 0; ks < 2; ks++) {
            bf16x8 af[4], bfr[4];
#pragma unroll
            for (int i = 0; i < 4; i++)
                af[i] = *(const bf16x8*)&sA[wm + 16 * i + lrow][ks * 32 + lq * 8];
#pragma unroll
            for (int j2 = 0; j2 < 4; j2++)
                bfr[j2] = *(const bf16x8*)&sB[wn + 16 * j2 + lrow][ks * 32 + lq * 8];
#pragma unroll
            for (int i = 0; i < 4; i++)
#pragma unroll
                for (int j2 = 0; j2 < 4; j2++)
                    acc[i][j2] = __builtin_amdgcn_mfma_f32_16x16x32_bf16(
                        af[i], bfr[j2], acc[i][j2], 0, 0, 0);
        }
        __syncthreads();
    }

#pragma unroll
    for (int j2 = 0; j2 < 4; j2++) {
        int ng = bn * TILE + wn + 16 * j2 + lrow;
        float bv = bias[e * D + ng];
#pragma unroll
        for (int i = 0; i < 4; i++) {
#pragma unroll
            for (int r = 0; r < 4; r++) {
                int mrow = wm + 16 * i + lq * 4 + r;
                int tok = s_idx[mrow];
                if (tok >= 0)
                    out[(size_t)tok * D + ng] = acc[i][j2][r] + bv;
            }
        }
    }
}

extern "C" void kernel_launch(void* const* d_in, const int* in_sizes, int n_in,
                              void* d_out, int out_size, void* d_ws, size_t ws_size,
                              hipStream_t stream) {
    const float* x    = (const float*)d_in[0];
    const int*   part = (const int*)d_in[1];
    const float* W    = (const float*)d_in[2];
    const float* b    = (const float*)d_in[3];
    float* out = (float*)d_out;

    const size_t xs_elems     = (size_t)MT_MAX * TILE_U16;        // u16
    const size_t wt_elems     = (size_t)N_EXPERTS * 4 * TILE_U16; // u16
    const size_t sorted_elems = (size_t)N_EXPERTS * T_TOKENS;     // int
    const size_t fast_bytes   = (xs_elems + wt_elems) * 2 + (sorted_elems + 8) * 4;
    const size_t slow_bytes   = (sorted_elems + 8) * 4;

    if (ws_size >= fast_bytes) {
        unsigned short* xs = (unsigned short*)d_ws;
        unsigned short* Wt = xs + xs_elems;
        int* sorted = (int*)(Wt + wt_elems);
        int* fill   = sorted + sorted_elems;

        hipMemsetAsync(fill, 0xFF, N_EXPERTS * sizeof(int), stream);   // fill = -1
        scatter_convw<<<SCATTER_BLOCKS + CONVW_BLOCKS, 256, 0, stream>>>(
            part, fill, sorted, W, Wt);
        gather_pack_x<<<MT_MAX, 256, 0, stream>>>(x, fill, sorted, xs);
        moe_gemm_pk<<<GRID_WG, 256, 0, stream>>>(xs, Wt, b, fill, sorted, out);
    } else if (ws_size >= slow_bytes) {
        int* sorted = (int*)d_ws;
        int* fill   = sorted + sorted_elems;

        hipMemsetAsync(fill, 0xFF, N_EXPERTS * sizeof(int), stream);
        scatter_convw<<<SCATTER_BLOCKS, 256, 0, stream>>>(
            part, fill, sorted, (const float*)nullptr, (unsigned short*)nullptr);
        moe_gemm_f32<<<GEMM_GRID, 256, 0, stream>>>(x, W, b, fill, sorted, out);
    }
}

// Round 8
// 160.559 us; speedup vs baseline: 1.1888x; 1.1888x over previous
//
#include <hip/hip_runtime.h>
#include <hip/hip_bf16.h>

#define N_EXPERTS 8
#define T_TOKENS 32768
#define D 512              // D_IN == D_OUT
#define TILE 128           // m-tile and n-tile
#define BK 64
#define NKK (D / BK)       // 8 k-steps
#define CHUNK 8192         // u16 per packed chunk (128 rows x 64 k = 16 KB)
#define TILE_U16 (NKK * CHUNK)   // 65536 u16 = 128 KB per packed m-tile
#define MT_MAX 264         // max global m-tiles (sum ceil(cnt_e/128) <= 263)
#define GRID_WG (MT_MAX * 4)     // 1056
#define SCATTER_BLOCKS (T_TOKENS / 256)   // 128
#define PACKW_BLOCKS 1024                 // one wave per W row (4096 rows)
#define GATHER_BLOCKS (MT_MAX * 32)       // 8448: one wave per packed row
#define LT_MAX 256
#define GEMM_GRID (N_EXPERTS * LT_MAX * 4)   // fallback grid

typedef __bf16 bf16x8 __attribute__((ext_vector_type(8)));
typedef float  f32x4  __attribute__((ext_vector_type(4)));
typedef unsigned short u16x8 __attribute__((ext_vector_type(8)));

__device__ __forceinline__ unsigned short f2bf(float f) {
    unsigned int u = __float_as_uint(f);
    u += 0x7FFFu + ((u >> 16) & 1u);   // round-to-nearest-even
    return (unsigned short)(u >> 16);
}

__device__ __forceinline__ u16x8 cvt8(float4 a, float4 b) {
    u16x8 o;
    o[0] = f2bf(a.x); o[1] = f2bf(a.y); o[2] = f2bf(a.z); o[3] = f2bf(a.w);
    o[4] = f2bf(b.x); o[5] = f2bf(b.y); o[6] = f2bf(b.z); o[7] = f2bf(b.w);
    return o;
}

__device__ __forceinline__ void gl2lds16(const void* g, void* l) {
    // async global->LDS, 16B/lane; LDS dest = wave-uniform base + lane*16
    __builtin_amdgcn_global_load_lds(
        (const __attribute__((address_space(1))) void*)g,
        (__attribute__((address_space(3))) void*)l, 16, 0, 0);
}

// ---- kernel 1: scatter token ids (fixed per-expert regions) + pack W ----
// Packed layout (both operands): per chunk, row-major [128 rows][8 slots of
// 16B]; slot s of row r holds global 16B k-block (s ^ (r&7)) -- the GEMM's
// fragment ds_read XOR hits all 32 banks, and staging is a LINEAR copy.
// One wave per W row: 2KB contiguous read, 8 x 128B packed writes.
__global__ __launch_bounds__(256) void scatter_convw(
        const int* __restrict__ p, int* __restrict__ fill, int* __restrict__ sorted,
        const float* __restrict__ W, unsigned short* __restrict__ Wt) {
    int bid = blockIdx.x;
    int tid = threadIdx.x;
    if (bid < SCATTER_BLOCKS) {
        __shared__ int lcount[N_EXPERTS];
        __shared__ int lbase[N_EXPERTS];
        if (tid < N_EXPERTS) lcount[tid] = 0;
        __syncthreads();
        int t = bid * 256 + tid;            // always < T_TOKENS
        int e = p[t];
        int lrank = atomicAdd(&lcount[e], 1);
        __syncthreads();
        if (tid < N_EXPERTS)
            lbase[tid] = (lcount[tid] > 0) ? atomicAdd(&fill[tid], lcount[tid]) : 0;
        __syncthreads();
        // fill starts at -1 (0xFF memset), atomicAdd returns old => first rank 0
        sorted[e * T_TOKENS + (lbase[e] + 1 + lrank)] = t;
    } else {
        int i2 = bid - SCATTER_BLOCKS;           // 0..1023
        int wave = tid >> 6, lane = tid & 63;
        int e = i2 >> 7;                         // 128 blocks/expert
        int gr = (i2 & 127) * 4 + wave;          // expert-local out row 0..511
        int bn = gr >> 7, row = gr & 127;
        int kk = lane >> 3, b = lane & 7;
        const float* src = W + ((size_t)e * D + gr) * D + lane * 8;
        float4 a = *(const float4*)src;
        float4 c = *(const float4*)(src + 4);
        unsigned short* base = Wt + (size_t)(e * 4 + bn) * TILE_U16 + kk * CHUNK;
        *(u16x8*)&base[row * 64 + ((b ^ (row & 7)) << 3)] = cvt8(a, c);
    }
}

// ---- kernel 2: gather x rows by token id into packed m-tiles ----
// one wave per row (max TLP): 2KB contiguous read; lane l emits one 16B bf16
// block into chunk (l>>3) at swizzled slot. Pad rows -> zeros.
__global__ __launch_bounds__(256) void gather_pack_x(
        const float* __restrict__ x, const int* __restrict__ fill,
        const int* __restrict__ sorted, unsigned short* __restrict__ xs) {
    int bid = blockIdx.x;
    int m = bid >> 5;                       // packed m-tile
    int rg = bid & 31;                      // 4-row group within tile

    int e = 0, lt = 0, tacc = 0, found = 0, cnt_e = 0;
#pragma unroll
    for (int i = 0; i < N_EXPERTS; i++) {
        int c = fill[i] + 1;                 // +1 trick (fill started at -1)
        int tiles = (c + TILE - 1) >> 7;
        if (!found && m < tacc + tiles) { e = i; lt = m - tacc; cnt_e = c; found = 1; }
        tacc += tiles;
    }
    if (!found) return;

    int tid = threadIdx.x, wave = tid >> 6, lane = tid & 63;
    int kk = lane >> 3, b = lane & 7;
    int row = rg * 4 + wave;                // row within tile 0..127
    int r = lt * TILE + row;
    int tok = (r < cnt_e) ? sorted[e * T_TOKENS + r] : -1;
    u16x8 v = (u16x8)0;
    if (tok >= 0) {
        const float* src = x + (size_t)tok * D + lane * 8;
        float4 a = *(const float4*)src;
        float4 c = *(const float4*)(src + 4);
        v = cvt8(a, c);
    }
    unsigned short* base = xs + (size_t)m * TILE_U16 + kk * CHUNK;
    *(u16x8*)&base[row * 64 + ((b ^ (row & 7)) << 3)] = v;
}

// ---- kernel 3: grouped GEMM on pre-packed operands (unchanged from r7) ----
// all-DMA dbuf, counted vmcnt(8), setprio, coalesced epilogue; every
// gl2lds16 reads 1KB CONTIGUOUS (src offset == dst offset).
// Grid 1056 = 264 global m-tiles x 4 bn; bn-siblings share bid%8 -> same XCD
// -> A-chunk fetched once per XCD, L2 serves the other 3.
__global__ __launch_bounds__(256, 2) void moe_gemm_pk(
        const unsigned short* __restrict__ xs, const unsigned short* __restrict__ Wt,
        const float* __restrict__ bias, const int* __restrict__ fill,
        const int* __restrict__ sorted, float* __restrict__ out) {
    __shared__ int s_idx[TILE];
    __shared__ unsigned short sA[2][TILE * BK];   // 32 KB
    __shared__ unsigned short sB[2][TILE * BK];   // 32 KB

    int bid = blockIdx.x;
    int w6 = bid >> 3;
    int m = (bid & 7) + (w6 >> 2) * 8;      // global m-tile 0..263
    int bn = w6 & 3;

    int e = 0, lt = 0, tacc = 0, found = 0, cnt_e = 0;
#pragma unroll
    for (int i = 0; i < N_EXPERTS; i++) {
        int c = fill[i] + 1;
        int tiles = (c + TILE - 1) >> 7;
        if (!found && m < tacc + tiles) { e = i; lt = m - tacc; cnt_e = c; found = 1; }
        tacc += tiles;
    }
    if (!found) return;
    int row0 = lt * TILE;

    int tid = threadIdx.x;
    if (tid < TILE) {
        int r = row0 + tid;
        s_idx[tid] = (r < cnt_e) ? sorted[e * T_TOKENS + r] : -1;
    }
    __syncthreads();   // also drains vmcnt -> DMA counting below starts clean

    int wave = tid >> 6, lane = tid & 63;
    int wm = (wave >> 1) * 64, wn = (wave & 1) * 64;
    int lrow = lane & 15, lq = lane >> 4;

    const unsigned short* gAc = xs + (size_t)m * TILE_U16;
    const unsigned short* gBc = Wt + (size_t)(e * 4 + bn) * TILE_U16;

#define STAGE(K, KB) do {                                                      \
    _Pragma("unroll") for (int t = 0; t < 4; t++)                              \
        gl2lds16(gAc + (size_t)(K) * CHUNK + (wave * 4 + t) * 512 + lane * 8,  \
                 &sA[KB][(wave * 4 + t) * 512]);                               \
    _Pragma("unroll") for (int t = 0; t < 4; t++)                              \
        gl2lds16(gBc + (size_t)(K) * CHUNK + (wave * 4 + t) * 512 + lane * 8,  \
                 &sB[KB][(wave * 4 + t) * 512]);                               \
} while (0)

    f32x4 acc[4][4];
#pragma unroll
    for (int i = 0; i < 4; i++)
#pragma unroll
        for (int j2 = 0; j2 < 4; j2++)
            acc[i][j2] = (f32x4){0.f, 0.f, 0.f, 0.f};

    STAGE(0, 0);   // prologue: stage(0) in flight (8 DMAs/thread)

#pragma unroll
    for (int step = 0; step < NKK; step++) {
        // top barrier: prev step's ds_reads retired -> other buffer is free
        asm volatile("s_waitcnt lgkmcnt(0)" ::: "memory");
        __builtin_amdgcn_s_barrier();
        __builtin_amdgcn_sched_barrier(0);
        if (step < NKK - 1) {
            STAGE(step + 1, (step + 1) & 1);   // issue next stage (8 DMAs)...
            __builtin_amdgcn_sched_barrier(0);
            // ...then wait ONLY for stage(step): 8 younger ops stay in flight
            asm volatile("s_waitcnt vmcnt(8)" ::: "memory");
        } else {
            asm volatile("s_waitcnt vmcnt(0)" ::: "memory");
        }
        __builtin_amdgcn_s_barrier();          // all waves' stage(step) visible
        __builtin_amdgcn_sched_barrier(0);
        const unsigned short* cA = sA[step & 1];
        const unsigned short* cB = sB[step & 1];
        __builtin_amdgcn_s_setprio(1);
#pragma unroll
        for (int ks = 0; ks < 2; ks++) {
            int cb = (ks * 4 + lq) ^ (lrow & 7);
            bf16x8 af[4], bfr[4];
#pragma unroll
            for (int i = 0; i < 4; i++)
                af[i] = *(const bf16x8*)&cA[(wm + 16 * i + lrow) * BK + cb * 8];
#pragma unroll
            for (int j2 = 0; j2 < 4; j2++)
                bfr[j2] = *(const bf16x8*)&cB[(wn + 16 * j2 + lrow) * BK + cb * 8];
#pragma unroll
            for (int i = 0; i < 4; i++)
#pragma unroll
                for (int j2 = 0; j2 < 4; j2++)
                    acc[i][j2] = __builtin_amdgcn_mfma_f32_16x16x32_bf16(
                        af[i], bfr[j2], acc[i][j2], 0, 0, 0);
        }
        __builtin_amdgcn_s_setprio(0);
    }
#undef STAGE

    // ---- coalesced epilogue: fold bias, stage C through LDS (reuse sA as
    // 64x128 f32 = 32 KB), write full 512B row-segments
#pragma unroll
    for (int j2 = 0; j2 < 4; j2++) {
        float bv = bias[e * D + bn * TILE + wn + 16 * j2 + lrow];
#pragma unroll
        for (int i = 0; i < 4; i++)
#pragma unroll
            for (int r = 0; r < 4; r++)
                acc[i][j2][r] += bv;
    }

    float* ct = (float*)&sA[0][0];   // 32 KB: 64 rows x 128 cols f32
#pragma unroll
    for (int p = 0; p < 2; p++) {
        // MFMA ds_reads done (p=0) / pass-0 ct reads done (p=1)
        asm volatile("s_waitcnt lgkmcnt(0)" ::: "memory");
        __builtin_amdgcn_s_barrier();
        if ((wave >> 1) == p) {      // the 2 waves owning rows [64p, 64p+64)
#pragma unroll
            for (int i = 0; i < 4; i++)
#pragma unroll
                for (int j2 = 0; j2 < 4; j2++)
#pragma unroll
                    for (int r = 0; r < 4; r++)
                        ct[(16 * i + lq * 4 + r) * TILE + wn + 16 * j2 + lrow]
                            = acc[i][j2][r];
        }
        asm volatile("s_waitcnt lgkmcnt(0)" ::: "memory");
        __builtin_amdgcn_s_barrier();
#pragma unroll
        for (int k = 0; k < 8; k++) {
            int u = tid + 256 * k;
            int row = u >> 5, ch = u & 31;
            int tok = s_idx[p * 64 + row];
            f32x4 v = *(const f32x4*)&ct[row * TILE + ch * 4];
            if (tok >= 0)
                *(f32x4*)&out[(size_t)tok * D + bn * TILE + ch * 4] = v;
        }
    }
}

// ---- fallback (tiny ws): fp32-load GEMM, fixed-region decode ----
__global__ __launch_bounds__(256) void moe_gemm_f32(
        const float* __restrict__ x, const float* __restrict__ W,
        const float* __restrict__ bias, const int* __restrict__ fill,
        const int* __restrict__ sorted, float* __restrict__ out) {
    __shared__ int s_idx[TILE];
    __shared__ unsigned short sA[TILE][BK + 8];
    __shared__ unsigned short sB[TILE][BK + 8];

    int bid = blockIdx.x;
    int e = bid & 7;
    int cnt = fill[e] + 1;
    int j = bid >> 3;
    int lt = j >> 2, bn = j & 3;
    int row0 = lt * TILE;
    if (row0 >= cnt) return;

    int tid = threadIdx.x;
    if (tid < TILE) {
        int r = row0 + tid;
        s_idx[tid] = (r < cnt) ? sorted[e * T_TOKENS + r] : -1;
    }
    __syncthreads();

    const float* Wbp = W + (size_t)e * D * D + (size_t)(bn * TILE) * D;

    f32x4 acc[4][4];
#pragma unroll
    for (int i = 0; i < 4; i++)
#pragma unroll
        for (int j2 = 0; j2 < 4; j2++)
            acc[i][j2] = (f32x4){0.f, 0.f, 0.f, 0.f};

    int wave = tid >> 6, lane = tid & 63;
    int wm = (wave >> 1) * 64, wn = (wave & 1) * 64;
    int lrow = lane & 15, lq = lane >> 4;

    for (int kk = 0; kk < D; kk += BK) {
#pragma unroll
        for (int i = 0; i < 8; i++) {
            int flat = tid + i * 256;
            int r = flat >> 4, c = (flat & 15) << 2;
            int tok = s_idx[r];
            float4 v = make_float4(0.f, 0.f, 0.f, 0.f);
            if (tok >= 0) v = *(const float4*)(x + (size_t)tok * D + kk + c);
            ushort4 w4;
            w4.x = f2bf(v.x); w4.y = f2bf(v.y); w4.z = f2bf(v.z); w4.w = f2bf(v.w);
            *(ushort4*)&sA[r][c] = w4;
        }
#pragma unroll
        for (int i = 0; i < 8; i++) {
            int flat = tid + i * 256;
            int r = flat >> 4, c = (flat & 15) << 2;
            float4 v = *(const float4*)(Wbp + (size_t)r * D + kk + c);
            ushort4 w4;
            w4.x = f2bf(v.x); w4.y = f2bf(v.y); w4.z = f2bf(v.z); w4.w = f2bf(v.w);
            *(ushort4*)&sB[r][c] = w4;
        }
        __syncthreads();
#pragma unroll
        for (int ks = 0; ks < 2; ks++) {
            bf16x8 af[4], bfr[4];
#pragma unroll
            for (int i = 0; i < 4; i++)
                af[i] = *(const bf16x8*)&sA[wm + 16 * i + lrow][ks * 32 + lq * 8];
#pragma unroll
            for (int j2 = 0; j2 < 4; j2++)
                bfr[j2] = *(const bf16x8*)&sB[wn + 16 * j2 + lrow][ks * 32 + lq * 8];
#pragma unroll
            for (int i = 0; i < 4; i++)
#pragma unroll
                for (int j2 = 0; j2 < 4; j2++)
                    acc[i][j2] = __builtin_amdgcn_mfma_f32_16x16x32_bf16(
                        af[i], bfr[j2], acc[i][j2], 0, 0, 0);
        }
        __syncthreads();
    }

#pragma unroll
    for (int j2 = 0; j2 < 4; j2++) {
        int ng = bn * TILE + wn + 16 * j2 + lrow;
        float bv = bias[e * D + ng];
#pragma unroll
        for (int i = 0; i < 4; i++) {
#pragma unroll
            for (int r = 0; r < 4; r++) {
                int mrow = wm + 16 * i + lq * 4 + r;
                int tok = s_idx[mrow];
                if (tok >= 0)
                    out[(size_t)tok * D + ng] = acc[i][j2][r] + bv;
            }
        }
    }
}

extern "C" void kernel_launch(void* const* d_in, const int* in_sizes, int n_in,
                              void* d_out, int out_size, void* d_ws, size_t ws_size,
                              hipStream_t stream) {
    const float* x    = (const float*)d_in[0];
    const int*   part = (const int*)d_in[1];
    const float* W    = (const float*)d_in[2];
    const float* b    = (const float*)d_in[3];
    float* out = (float*)d_out;

    const size_t xs_elems     = (size_t)MT_MAX * TILE_U16;        // u16
    const size_t wt_elems     = (size_t)N_EXPERTS * 4 * TILE_U16; // u16
    const size_t sorted_elems = (size_t)N_EXPERTS * T_TOKENS;     // int
    const size_t fast_bytes   = (xs_elems + wt_elems) * 2 + (sorted_elems + 8) * 4;
    const size_t slow_bytes   = (sorted_elems + 8) * 4;

    if (ws_size >= fast_bytes) {
        unsigned short* xs = (unsigned short*)d_ws;
        unsigned short* Wt = xs + xs_elems;
        int* sorted = (int*)(Wt + wt_elems);
        int* fill   = sorted + sorted_elems;

        hipMemsetAsync(fill, 0xFF, N_EXPERTS * sizeof(int), stream);   // fill = -1
        scatter_convw<<<SCATTER_BLOCKS + PACKW_BLOCKS, 256, 0, stream>>>(
            part, fill, sorted, W, Wt);
        gather_pack_x<<<GATHER_BLOCKS, 256, 0, stream>>>(x, fill, sorted, xs);
        moe_gemm_pk<<<GRID_WG, 256, 0, stream>>>(xs, Wt, b, fill, sorted, out);
    } else if (ws_size >= slow_bytes) {
        int* sorted = (int*)d_ws;
        int* fill   = sorted + sorted_elems;

        hipMemsetAsync(fill, 0xFF, N_EXPERTS * sizeof(int), stream);
        scatter_convw<<<SCATTER_BLOCKS, 256, 0, stream>>>(
            part, fill, sorted, (const float*)nullptr, (unsigned short*)nullptr);
        moe_gemm_f32<<<GEMM_GRID, 256, 0, stream>>>(x, W, b, fill, sorted, out);
    }
}